// Round 1
// baseline (341.858 us; speedup 1.0000x reference)
//
#include <hip/hip_runtime.h>
#include <math.h>

#define NS 4096
#define NV 65536
#define DDIM 128
#define EPSV 1e-6f
#define NCHUNK 16
#define TILES_PER_CHUNK 32
#define FLTMAX 3.402823466e+38f
#define IMAX 0x7fffffff

// ws layout, 4-byte units unless noted
#define XSQ_F    0              // 4096 floats
#define XSUM_F   4096           // 4096 floats
#define PART_F   8192           // float2 per (sample, chunk): 4096*16*2 floats
#define D12_F    139264         // float2 per sample: 8192 floats
#define CNT_I    147456         // 16 ints
#define CELL1_I  147472         // 4096 ints
#define CELL2_I  151568         // 4096 ints
#define BUCKET_I 155664         // 16*4096 ints (ends 221200 < 401408)
#define WS_TILED_BYTE 1605632   // tiled V region (bytes), unchanged
#define TILE_BYTES 65536        // 8 s x 2 split x 2 q x 128 m x 16B
#define TILE_STRIDE 66560       // + 1KB cj slot (512B cj + pad)

typedef __attribute__((ext_vector_type(8)))  __bf16        bf16x8;
typedef __attribute__((ext_vector_type(8)))  unsigned short ush8;
typedef __attribute__((ext_vector_type(4)))  unsigned short ush4;
typedef __attribute__((ext_vector_type(16))) float          f32x16;

typedef const __attribute__((address_space(1))) unsigned int* gp_t;
typedef __attribute__((address_space(3))) unsigned int*       lp_t;

__device__ __forceinline__ void async_cp16(const void* g, void* l) {
    __builtin_amdgcn_global_load_lds((gp_t)g, (lp_t)l, 16, 0, 0);
}

__device__ __forceinline__ unsigned short f2bf(float x) {
    unsigned u = __builtin_bit_cast(unsigned, x);
    u += 0x7FFFu + ((u >> 16) & 1u);      // RNE
    return (unsigned short)(u >> 16);
}
__device__ __forceinline__ float bf2f(unsigned short h) {
    unsigned u = ((unsigned)h) << 16;
    return __builtin_bit_cast(float, u);
}

// stage one 128x128 tile (+ cj slot) into LDS
__device__ __forceinline__ void stage_tile(const char* src, char* lds, int tid) {
    #pragma unroll
    for (int i = 0; i < 16; i++) {
        int off = (i * 256 + tid) * 16;
        async_cp16(src + off, lds + off);
    }
    if (tid < 64) {
        int off = TILE_BYTES + tid * 16;
        async_cp16(src + off, lds + off);
    }
}

// this lane's B fragments: sample row scaled by -2 (exact), hi/lo bf16 split
__device__ __forceinline__ void load_bfrag(const float* __restrict__ samples,
                                           int srow, int q, ush8* bh, ush8* bl) {
    const float4* s4 = (const float4*)samples;
    #pragma unroll
    for (int s = 0; s < 8; s++) {
        float4 x0 = s4[(size_t)srow * 32 + s * 4 + q * 2];
        float4 x1 = s4[(size_t)srow * 32 + s * 4 + q * 2 + 1];
        float xs[8] = {x0.x, x0.y, x0.z, x0.w, x1.x, x1.y, x1.z, x1.w};
        #pragma unroll
        for (int j = 0; j < 8; j++) {
            float y = -2.0f * xs[j];
            unsigned short hh = f2bf(y);
            bh[s][j] = hh;
            bl[s][j] = f2bf(y - bf2f(hh));
        }
    }
}

// MFMA chain for one staged tile; acc starts at cj and accumulates -2*x.v.
// acc[mi][r] holds t = cj - 2*dot for code (mi*32 + (r>>2)*8 + (r&3) + 4q)
// of this tile, sample column l31. Chain order is fixed by data dependence,
// so pass A (topk) and pass B (recover) produce bit-identical values.
__device__ __forceinline__ void tile_mfma(const char* lds, const ush8* bh, const ush8* bl,
                                          int q, int l31, f32x16 acc[4]) {
    #pragma unroll
    for (int mi = 0; mi < 4; mi++) {
        #pragma unroll
        for (int g = 0; g < 4; g++) {
            float4 cj = *(const float4*)(lds + TILE_BYTES + (size_t)(mi * 32 + g * 8 + 4 * q) * 4);
            acc[mi][g * 4 + 0] = cj.x;
            acc[mi][g * 4 + 1] = cj.y;
            acc[mi][g * 4 + 2] = cj.z;
            acc[mi][g * 4 + 3] = cj.w;
        }
    }
    #pragma unroll
    for (int s = 0; s < 8; s++) {
        bf16x8 bhs = __builtin_bit_cast(bf16x8, bh[s]);
        bf16x8 bls = __builtin_bit_cast(bf16x8, bl[s]);
        #pragma unroll
        for (int mi = 0; mi < 4; mi++) {
            bf16x8 ah = *(const bf16x8*)(lds + (size_t)((((s * 2 + 0) * 2 + q) * 128) + mi * 32 + l31) * 16);
            bf16x8 al = *(const bf16x8*)(lds + (size_t)((((s * 2 + 1) * 2 + q) * 128) + mi * 32 + l31) * 16);
            acc[mi] = __builtin_amdgcn_mfma_f32_32x32x16_bf16(ah, bhs, acc[mi], 0, 0, 0);
            acc[mi] = __builtin_amdgcn_mfma_f32_32x32x16_bf16(ah, bls, acc[mi], 0, 0, 0);
            acc[mi] = __builtin_amdgcn_mfma_f32_32x32x16_bf16(al, bhs, acc[mi], 0, 0, 0);
        }
    }
}

// ---- K1: fused prep. Blocks [0,512): V tile -> tiled bf16 hi/lo + cj slot
//          Blocks [512,1536): sample row stats (x_sq, x_sum); zero CNT ----
__global__ void vq_prep(const float* __restrict__ samples,
                        const float* __restrict__ V,
                        char* __restrict__ ws) {
    float* ws_f = (float*)ws;
    int* ws_i = (int*)ws;
    const int b = blockIdx.x;
    const int tid = threadIdx.x;
    if (b >= NV / 128) {
        if (b == NV / 128 && tid < NCHUNK) ws_i[CNT_I + tid] = 0;
        int row = (b - NV / 128) * 4 + (tid >> 6);
        int lane = tid & 63;
        float2 v = ((const float2*)(samples + (size_t)row * DDIM))[lane];
        float s = v.x + v.y;
        float q = v.x * v.x + v.y * v.y;
        #pragma unroll
        for (int off = 32; off >= 1; off >>= 1) {
            s += __shfl_xor(s, off);
            q += __shfl_xor(q, off);
        }
        if (lane == 0) { ws_f[XSQ_F + row] = q; ws_f[XSUM_F + row] = s; }
        return;
    }
    const int tile = b;
    char* dst = ws + WS_TILED_BYTE + (size_t)tile * TILE_STRIDE;
    const float4* v4 = (const float4*)V;
    #pragma unroll
    for (int i = 0; i < 16; i++) {
        int flat = i * 256 + tid;                 // row handled by 32 consecutive lanes
        int row = flat >> 5;
        int kq = flat & 31;
        float4 g = v4[(size_t)(tile * 128 + row) * 32 + kq];
        float s = g.x + g.y + g.z + g.w;
        float q2 = g.x * g.x + g.y * g.y + g.z * g.z + g.w * g.w;
        #pragma unroll
        for (int off = 16; off >= 1; off >>= 1) { // reduce within the 32-lane group
            s += __shfl_xor(s, off);
            q2 += __shfl_xor(q2, off);
        }
        if ((tid & 31) == 0)
            *(float*)(dst + TILE_BYTES + row * 4) = q2 - 2.0f * EPSV * s;   // cj
        int k0 = kq * 4;
        int sI = k0 >> 4, qI = (k0 >> 3) & 1, j0 = k0 & 7;
        float xs[4] = {g.x, g.y, g.z, g.w};
        ush4 h, l;
        #pragma unroll
        for (int e = 0; e < 4; e++) {
            unsigned short hh = f2bf(xs[e]);
            h[e] = hh;
            l[e] = f2bf(xs[e] - bf2f(hh));
        }
        *(ush4*)(dst + ((((sI * 2 + 0) * 2 + qI) * 128) + row) * 16 + j0 * 2) = h;
        *(ush4*)(dst + ((((sI * 2 + 1) * 2 + qI) * 128) + row) * 16 + j0 * 2) = l;
    }
}

// ---- K2: MFMA GEMM + value-only top-2 (3 VALU ops/elem, no index tracking) ----
__global__ __launch_bounds__(256, 2)
void vq_gemm_topk(const float* __restrict__ samples, char* __restrict__ ws) {
    __shared__ __align__(16) char lds[TILE_STRIDE];
    const int tid = threadIdx.x;
    const int w = tid >> 6, lane = tid & 63;
    const int l31 = lane & 31, q = lane >> 5;
    const int st = blockIdx.x;
    const int chunk = blockIdx.y;
    const int nrow = st * 128 + w * 32 + l31;

    ush8 bh[8], bl[8];
    load_bfrag(samples, nrow, q, bh, bl);

    // 4 independent running top-2 pairs (per mi) to shorten dependency chains
    float rd1[4], rd2[4];
    #pragma unroll
    for (int mi = 0; mi < 4; mi++) { rd1[mi] = FLTMAX; rd2[mi] = FLTMAX; }

    const char* tile0 = ws + WS_TILED_BYTE + (size_t)(chunk * TILES_PER_CHUNK) * TILE_STRIDE;

    for (int it = 0; it < TILES_PER_CHUNK; it++) {
        stage_tile(tile0 + (size_t)it * TILE_STRIDE, lds, tid);
        __syncthreads();
        f32x16 acc[4];
        tile_mfma(lds, bh, bl, q, l31, acc);
        #pragma unroll
        for (int mi = 0; mi < 4; mi++) {
            #pragma unroll
            for (int r = 0; r < 16; r++) {
                float v = acc[mi][r];
                rd2[mi] = fminf(rd2[mi], fmaxf(rd1[mi], v));
                rd1[mi] = fminf(rd1[mi], v);
            }
        }
        __syncthreads();
    }

    // merge the 4 sorted pairs
    float d1 = rd1[0], d2 = rd2[0];
    #pragma unroll
    for (int mi = 1; mi < 4; mi++) {
        float t = fmaxf(d1, rd1[mi]);
        d1 = fminf(d1, rd1[mi]);
        d2 = fminf(fminf(t, d2), rd2[mi]);
    }
    // merge the two lanes (q=0,1) holding the same sample
    {
        float od1 = __shfl_xor(d1, 32), od2 = __shfl_xor(d2, 32);
        float t = fmaxf(d1, od1);
        d1 = fminf(d1, od1);
        d2 = fminf(fminf(t, d2), od2);
    }
    if (q == 0) {
        float2* part = (float2*)((float*)ws + PART_F);
        part[(size_t)nrow * NCHUNK + chunk] = make_float2(d1, d2);
    }
}

// ---- K3: merge chunk partials -> global top-2 VALUES, write 'a', build
//          per-chunk rescan buckets (wave-aggregated atomics) ----
__global__ void vq_merge(float* __restrict__ ws_f, float* __restrict__ out) {
    const int m = blockIdx.x * 256 + threadIdx.x;
    const int lane = threadIdx.x & 63;
    int* ws_i = (int*)ws_f;
    const float2* part = (const float2*)(ws_f + PART_F);
    float2 p[NCHUNK];
    float g1 = FLTMAX, g2 = FLTMAX;
    #pragma unroll
    for (int c = 0; c < NCHUNK; c++) {
        p[c] = part[(size_t)m * NCHUNK + c];
        float t = fmaxf(g1, p[c].x);
        g1 = fminf(g1, p[c].x);
        g2 = fminf(fminf(t, g2), p[c].y);
    }
    ((float2*)(ws_f + D12_F))[m] = make_float2(g1, g2);
    ws_i[CELL1_I + m] = IMAX;
    ws_i[CELL2_I + m] = IMAX;
    float ci = ws_f[XSQ_F + m] + 2.0f * EPSV * ws_f[XSUM_F + m] + (float)DDIM * EPSV * EPSV;
    out[2 * NS + m] = expf(-sqrtf(fmaxf(ci + g1, 0.0f)));
    // any element equal to g1 or g2 is inside its chunk's top-2, so equality
    // on chunk partials is a complete filter for which chunks to rescan
    #pragma unroll
    for (int c = 0; c < NCHUNK; c++) {
        bool want = (p[c].x == g1) || (p[c].x == g2) || (p[c].y == g2);
        unsigned long long mk = __ballot(want);
        if (mk) {
            int leader = (int)__ffsll(mk) - 1;
            int base = 0;
            if (lane == leader) base = atomicAdd(&ws_i[CNT_I + c], (int)__popcll(mk));
            base = __shfl(base, leader);
            if (want) {
                int pos = base + (int)__popcll(mk & ((1ull << lane) - 1ull));
                ws_i[BUCKET_I + c * NS + pos] = m;
            }
        }
    }
}

// ---- K4: bit-exact rescan of winning (sample, chunk) pairs; recover indices
//          by float equality. atomicMin two-slot insert == reference tiebreak ----
__global__ __launch_bounds__(256, 2)
void vq_recover(const float* __restrict__ samples, char* __restrict__ ws) {
    __shared__ __align__(16) char lds[TILE_STRIDE];
    const int tid = threadIdx.x;
    const int w = tid >> 6, lane = tid & 63;
    const int l31 = lane & 31, q = lane >> 5;
    const int tg = blockIdx.x;      // tile group 0..7 (4 tiles each)
    const int chunk = blockIdx.z;   // 0..15
    int* ws_i = (int*)ws;
    float* ws_f = (float*)ws;
    const int cnt = ws_i[CNT_I + chunk];
    const char* tile0 = ws + WS_TILED_BYTE + (size_t)(chunk * TILES_PER_CHUNK) * TILE_STRIDE;

    for (int sy = blockIdx.y; sy * 128 < cnt; sy += 4) {
        int slot = sy * 128 + w * 32 + l31;
        bool valid = slot < cnt;
        int sample = valid ? ws_i[BUCKET_I + chunk * NS + slot] : 0;
        ush8 bh[8], bl[8];
        load_bfrag(samples, sample, q, bh, bl);
        float d1t, d2t;
        if (valid) {
            float2 dt = ((const float2*)(ws_f + D12_F))[sample];
            d1t = dt.x; d2t = dt.y;
        } else {
            d1t = __int_as_float(0x7fc00000);   // NaN: never matches
            d2t = d1t;
        }
        #pragma unroll 1
        for (int it = tg * 4; it < tg * 4 + 4; it++) {
            stage_tile(tile0 + (size_t)it * TILE_STRIDE, lds, tid);
            __syncthreads();
            f32x16 acc[4];
            tile_mfma(lds, bh, bl, q, l31, acc);
            const int cbase = chunk * 4096 + it * 128 + 4 * q;
            #pragma unroll
            for (int mi = 0; mi < 4; mi++) {
                #pragma unroll
                for (int r = 0; r < 16; r++) {
                    float v = acc[mi][r];
                    if (v == d1t) {
                        int idx = cbase + mi * 32 + (r >> 2) * 8 + (r & 3);
                        int old = atomicMin(&ws_i[CELL1_I + sample], idx);
                        int loser = old > idx ? old : idx;
                        atomicMin(&ws_i[CELL2_I + sample], loser);
                    } else if (v == d2t) {
                        int idx = cbase + mi * 32 + (r >> 2) * 8 + (r & 3);
                        atomicMin(&ws_i[CELL2_I + sample], idx);
                    }
                }
            }
            __syncthreads();
        }
    }
}

// ---- K5: write index outputs ----
__global__ void vq_finalize(const char* __restrict__ ws, float* __restrict__ out) {
    const int m = blockIdx.x * 256 + threadIdx.x;
    const int* ws_i = (const int*)ws;
    out[m]      = (float)ws_i[CELL1_I + m];
    out[NS + m] = (float)ws_i[CELL2_I + m];
}

extern "C" void kernel_launch(void* const* d_in, const int* in_sizes, int n_in,
                              void* d_out, int out_size, void* d_ws, size_t ws_size,
                              hipStream_t stream) {
    (void)in_sizes; (void)n_in; (void)out_size; (void)ws_size;
    const float* samples = (const float*)d_in[0];
    const float* V = (const float*)d_in[1];
    float* out = (float*)d_out;
    float* ws_f = (float*)d_ws;
    char*  ws_b = (char*)d_ws;

    vq_prep<<<dim3(NV / 128 + NS / 4), 256, 0, stream>>>(samples, V, ws_b);
    vq_gemm_topk<<<dim3(NS / 128, NCHUNK), 256, 0, stream>>>(samples, ws_b);
    vq_merge<<<dim3(NS / 256), 256, 0, stream>>>(ws_f, out);
    vq_recover<<<dim3(8, 4, NCHUNK), 256, 0, stream>>>(samples, ws_b);
    vq_finalize<<<dim3(NS / 256), 256, 0, stream>>>(ws_b, out);
}